// Round 15
// baseline (4880.827 us; speedup 1.0000x reference)
//
#include <hip/hip_runtime.h>
#include <hip/hip_fp16.h>

#define T_LEN 8192
#define N_NODES 33
#define N_EDGES 64
#define DIM_IN 3
#define D_H 64
#define D_LSTM 128
#define N_CLS 5
#define TB 4   // timesteps per block in kernel 1

typedef float v2f __attribute__((ext_vector_type(2)));
typedef float v4f __attribute__((ext_vector_type(4)));

// ---------------------------------------------------------------------------
// Kernel 1: graph conv x2 + relu + mean over nodes + input-side LSTM projection
// Writes A in (T, 128, 4) layout: A[(t*128+q)*4 + g] = gate g of unit q
// (g: 0=i, 1=f, 2=g, 3=o).  LSTM thread (q,kq) scalar-loads its own gate.
// ---------------------------------------------------------------------------
__global__ __launch_bounds__(64, 2) void gnn_proj_kernel(
    const float* __restrict__ x,        // (T,33,3)
    const int*   __restrict__ esrc,     // (64,)
    const int*   __restrict__ edst,     // (64,)
    const float* __restrict__ W_rel1,   // (64,3)
    const float* __restrict__ b_rel1,   // (64,)
    const float* __restrict__ W_root1,  // (64,3)
    const float* __restrict__ W_rel2,   // (64,64)
    const float* __restrict__ b_rel2,   // (64,)
    const float* __restrict__ W_root2,  // (64,64)
    const float* __restrict__ W_ih,     // (512,64)
    const float* __restrict__ b_ih,     // (512,)
    const float* __restrict__ b_hh,     // (512,)
    float* __restrict__ A)              // (T,128,4)  [workspace]
{
    const int t0 = blockIdx.x * TB;
    const int j  = threadIdx.x;   // 0..63

    __shared__ __align__(16) float x_s[N_NODES][DIM_IN];
    __shared__ __align__(16) float agg1[N_NODES][DIM_IN];
    __shared__ __align__(16) float h1[N_NODES][D_H];
    __shared__ __align__(16) float agg2[N_NODES][D_H];
    __shared__ __align__(16) float seq_s[TB][D_H];
    __shared__ int es[N_EDGES], ed[N_EDGES];

    es[j] = esrc[j];
    ed[j] = edst[j];

    const float wr1_0 = W_rel1[j*3+0], wr1_1 = W_rel1[j*3+1], wr1_2 = W_rel1[j*3+2];
    const float wt1_0 = W_root1[j*3+0], wt1_1 = W_root1[j*3+1], wt1_2 = W_root1[j*3+2];
    const float br1 = b_rel1[j];
    const float br2 = b_rel2[j];

    float wr2[D_H], wt2[D_H];
    #pragma unroll
    for (int k = 0; k < D_H; ++k) {
        wr2[k] = W_rel2[j*D_H + k];
        wt2[k] = W_root2[j*D_H + k];
    }

    for (int tt = 0; tt < TB; ++tt) {
        const int t = t0 + tt;
        __syncthreads();

        const float* xt = x + (size_t)t * (N_NODES * DIM_IN);
        for (int i = j; i < N_NODES * DIM_IN; i += 64) x_s[0][i] = xt[i];
        __syncthreads();

        if (j < N_NODES) {
            float a0 = 0.f, a1 = 0.f, a2 = 0.f;
            for (int e = 0; e < N_EDGES; ++e) {
                if (ed[e] == j) {
                    a0 += x_s[es[e]][0];
                    a1 += x_s[es[e]][1];
                    a2 += x_s[es[e]][2];
                }
            }
            agg1[j][0] = a0; agg1[j][1] = a1; agg1[j][2] = a2;
        }
        __syncthreads();

        for (int n = 0; n < N_NODES; ++n) {
            float v = br1
                + agg1[n][0]*wr1_0 + agg1[n][1]*wr1_1 + agg1[n][2]*wr1_2
                + x_s[n][0]*wt1_0  + x_s[n][1]*wt1_1  + x_s[n][2]*wt1_2;
            h1[n][j]  = v;
            agg2[n][j] = 0.f;
        }
        __syncthreads();

        for (int e = 0; e < N_EDGES; ++e) {
            agg2[ed[e]][j] += h1[es[e]][j];
        }
        __syncthreads();

        float seqv = 0.f;
        for (int n = 0; n < N_NODES; ++n) {
            const float4* ag4 = (const float4*)agg2[n];
            const float4* h4  = (const float4*)h1[n];
            float acc0 = br2, acc1 = 0.f, acc2 = 0.f, acc3 = 0.f;
            #pragma unroll
            for (int k4 = 0; k4 < D_H/4; ++k4) {
                float4 av = ag4[k4];
                float4 hv = h4[k4];
                acc0 += av.x * wr2[4*k4+0] + hv.x * wt2[4*k4+0];
                acc1 += av.y * wr2[4*k4+1] + hv.y * wt2[4*k4+1];
                acc2 += av.z * wr2[4*k4+2] + hv.z * wt2[4*k4+2];
                acc3 += av.w * wr2[4*k4+3] + hv.w * wt2[4*k4+3];
            }
            float acc = (acc0 + acc1) + (acc2 + acc3);
            seqv += fmaxf(acc, 0.f);
        }
        seq_s[tt][j] = seqv * (1.0f / 33.0f);
    }
    __syncthreads();

    #pragma unroll
    for (int m = 0; m < 8; ++m) {
        const int o = m * 64 + j;
        const float bias = b_ih[o] + b_hh[o];
        const float4* w4 = (const float4*)(W_ih + (size_t)o * D_H);
        float acc[TB];
        #pragma unroll
        for (int tt = 0; tt < TB; ++tt) acc[tt] = bias;
        #pragma unroll
        for (int k4 = 0; k4 < D_H/4; ++k4) {
            float4 wv = w4[k4];
            #pragma unroll
            for (int tt = 0; tt < TB; ++tt) {
                const float4* s4 = (const float4*)seq_s[tt];
                float4 sv = s4[k4];
                acc[tt] += sv.x*wv.x + sv.y*wv.y + sv.z*wv.z + sv.w*wv.w;
            }
        }
        // (T,128,4) layout: q = o&127, g = o>>7
        #pragma unroll
        for (int tt = 0; tt < TB; ++tt) {
            A[((size_t)(t0 + tt) * 128 + (o & 127)) * 4 + (o >> 7)] = acc[tt];
        }
    }
}

// ---------------------------------------------------------------------------
// Kernel 2 (round 15): full-asm LSTM, MAC block = v_pk_fma_f16 (FULL-rate
// packed f16: 2 MACs / 2 cyc, vs dot2/pk_fma_f32 at 4 cyc measured r13/r14).
// Accumulate in f16x2 (4 independent chains), fold hi/lo to f32 before the
// proven DPP reduce-scatter.  Staged lgkmcnt(3/2/1/0) so each read-group's
// MACs hide the next ds_read's latency.  Everything else identical to r14
// (reduce / per-lane nonlin / scalar A prefetch / f16 h exchange).
// Register map: v0-63 packed f16 weights | v128-143 h (f16 dwords) |
// v160-163 accs | v168/v172 A dbuf | v176-190 temps | v181 c.
// ---------------------------------------------------------------------------

#define CVTPK(D,S0,S1) \
  "v_cvt_f16_f32 v190, v" #S0 "\n\t" \
  "v_cvt_f16_f32 v191, v" #S1 "\n\t" \
  "v_and_b32 v190, 0xffff, v190\n\t" \
  "v_lshlrev_b32 v191, 16, v191\n\t" \
  "v_or_b32 v" #D ", v190, v191\n\t"

#define ROWPACK(D0,D1,D2,D3,D4,D5,D6,D7,D8,D9,D10,D11,D12,D13,D14,D15) \
  CVTPK(D0,128,129) CVTPK(D1,130,131) CVTPK(D2,132,133) CVTPK(D3,134,135) \
  CVTPK(D4,136,137) CVTPK(D5,138,139) CVTPK(D6,140,141) CVTPK(D7,142,143) \
  CVTPK(D8,144,145) CVTPK(D9,146,147) CVTPK(D10,148,149) CVTPK(D11,150,151) \
  CVTPK(D12,152,153) CVTPK(D13,154,155) CVTPK(D14,156,157) CVTPK(D15,158,159)

#define ROWLOAD(WA) \
  "global_load_dwordx4 v[128:131], %[" #WA "], off\n\t" \
  "global_load_dwordx4 v[132:135], %[" #WA "], off offset:16\n\t" \
  "global_load_dwordx4 v[136:139], %[" #WA "], off offset:32\n\t" \
  "global_load_dwordx4 v[140:143], %[" #WA "], off offset:48\n\t" \
  "global_load_dwordx4 v[144:147], %[" #WA "], off offset:64\n\t" \
  "global_load_dwordx4 v[148:151], %[" #WA "], off offset:80\n\t" \
  "global_load_dwordx4 v[152:155], %[" #WA "], off offset:96\n\t" \
  "global_load_dwordx4 v[156:159], %[" #WA "], off offset:112\n\t" \
  "s_waitcnt vmcnt(0)\n\t"

// packed f16 FMA: 4 gates for h dword H against weight dwords A,B,C,D
#define PKM4(H, A,B,C,D) \
  "v_pk_mul_f16 v160, v" #H ", v" #A "\n\t" \
  "v_pk_mul_f16 v161, v" #H ", v" #B "\n\t" \
  "v_pk_mul_f16 v162, v" #H ", v" #C "\n\t" \
  "v_pk_mul_f16 v163, v" #H ", v" #D "\n\t"
#define PKF4(H, A,B,C,D) \
  "v_pk_fma_f16 v160, v" #H ", v" #A ", v160\n\t" \
  "v_pk_fma_f16 v161, v" #H ", v" #B ", v161\n\t" \
  "v_pk_fma_f16 v162, v" #H ", v" #C ", v162\n\t" \
  "v_pk_fma_f16 v163, v" #H ", v" #D ", v163\n\t"

// P = prefetch dest reg (next step's A), PC = consume reg (this step's A)
#define HALF(P, PC, R0,R1,R2,R3, WOFF) \
  "v_add_u32 v190, s80, %[at]\n\t" \
  "global_load_dword v" #P ", v190, %[ab]\n\t" \
  "s_add_u32 s80, s80, 2048\n\t" \
  "s_cmp_lg_u32 s80, 0x1000000\n\t" \
  "s_cselect_b32 s80, s80, 0\n\t" \
  "ds_read_b128 v[128:131], %[rd] offset:" #R0 "\n\t" \
  "ds_read_b128 v[132:135], %[rd] offset:" #R1 "\n\t" \
  "ds_read_b128 v[136:139], %[rd] offset:" #R2 "\n\t" \
  "ds_read_b128 v[140:143], %[rd] offset:" #R3 "\n\t" \
  "s_waitcnt lgkmcnt(3)\n\t" \
  PKM4(128, 0,16,32,48) \
  PKF4(129, 1,17,33,49) \
  PKF4(130, 2,18,34,50) \
  PKF4(131, 3,19,35,51) \
  "s_waitcnt lgkmcnt(2)\n\t" \
  PKF4(132, 4,20,36,52) \
  PKF4(133, 5,21,37,53) \
  PKF4(134, 6,22,38,54) \
  PKF4(135, 7,23,39,55) \
  "s_waitcnt lgkmcnt(1)\n\t" \
  PKF4(136, 8,24,40,56) \
  PKF4(137, 9,25,41,57) \
  PKF4(138, 10,26,42,58) \
  PKF4(139, 11,27,43,59) \
  "s_waitcnt lgkmcnt(0)\n\t" \
  PKF4(140, 12,28,44,60) \
  PKF4(141, 13,29,45,61) \
  PKF4(142, 14,30,46,62) \
  PKF4(143, 15,31,47,63) \
  /* fold f16x2 accs (hi+lo) into f32 v160-163 */ \
  "v_lshrrev_b32 v184, 16, v160\n\t" \
  "v_lshrrev_b32 v185, 16, v161\n\t" \
  "v_lshrrev_b32 v186, 16, v162\n\t" \
  "v_lshrrev_b32 v187, 16, v163\n\t" \
  "v_cvt_f32_f16 v160, v160\n\t" \
  "v_cvt_f32_f16 v161, v161\n\t" \
  "v_cvt_f32_f16 v162, v162\n\t" \
  "v_cvt_f32_f16 v163, v163\n\t" \
  "v_cvt_f32_f16 v184, v184\n\t" \
  "v_cvt_f32_f16 v185, v185\n\t" \
  "v_cvt_f32_f16 v186, v186\n\t" \
  "v_cvt_f32_f16 v187, v187\n\t" \
  "v_add_f32 v160, v160, v184\n\t" \
  "v_add_f32 v161, v161, v185\n\t" \
  "v_add_f32 v162, v162, v186\n\t" \
  "v_add_f32 v163, v163, v187\n\t" \
  /* quad reduce-scatter: accs v160=i v161=f v162=g v163=o */ \
  "v_mov_b32_dpp v184, v160 quad_perm:[2,3,0,1] row_mask:0xf bank_mask:0xf\n\t" \
  "v_mov_b32_dpp v185, v161 quad_perm:[2,3,0,1] row_mask:0xf bank_mask:0xf\n\t" \
  "v_mov_b32_dpp v186, v162 quad_perm:[2,3,0,1] row_mask:0xf bank_mask:0xf\n\t" \
  "v_mov_b32_dpp v187, v163 quad_perm:[2,3,0,1] row_mask:0xf bank_mask:0xf\n\t" \
  "v_add_f32 v160, v160, v184\n\t" \
  "v_add_f32 v161, v161, v185\n\t" \
  "v_add_f32 v162, v162, v186\n\t" \
  "v_add_f32 v163, v163, v187\n\t" \
  "v_cndmask_b32 v184, v160, v162, %[mb1]\n\t" \
  "v_cndmask_b32 v185, v161, v163, %[mb1]\n\t" \
  "s_nop 1\n\t" \
  "v_mov_b32_dpp v186, v184 quad_perm:[1,0,3,2] row_mask:0xf bank_mask:0xf\n\t" \
  "v_mov_b32_dpp v187, v185 quad_perm:[1,0,3,2] row_mask:0xf bank_mask:0xf\n\t" \
  "v_add_f32 v184, v184, v186\n\t" \
  "v_add_f32 v185, v185, v187\n\t" \
  "v_cndmask_b32 v184, v184, v185, %[mb0]\n\t"   /* lane kq: sum of gate kq */ \
  "s_waitcnt vmcnt(1)\n\t" \
  "v_add_f32 v184, v184, v" #PC "\n\t" \
  /* per-lane nonlin: y=rcp(1+exp2(m1*x)); y'=y*sc+ad */ \
  "v_mul_f32 v186, %[m1], v184\n\t" \
  "v_exp_f32 v186, v186\n\t" \
  "s_nop 1\n\t" \
  "v_add_f32 v186, 1.0, v186\n\t" \
  "v_rcp_f32 v186, v186\n\t" \
  "s_nop 1\n\t" \
  "v_fma_f32 v186, v186, %[sc], %[ad]\n\t" \
  "s_nop 1\n\t" \
  /* quad broadcast: si,sf,tg,so */ \
  "v_mov_b32_dpp v176, v186 quad_perm:[0,0,0,0] row_mask:0xf bank_mask:0xf\n\t" \
  "v_mov_b32_dpp v177, v186 quad_perm:[1,1,1,1] row_mask:0xf bank_mask:0xf\n\t" \
  "v_mov_b32_dpp v179, v186 quad_perm:[2,2,2,2] row_mask:0xf bank_mask:0xf\n\t" \
  "v_mov_b32_dpp v178, v186 quad_perm:[3,3,3,3] row_mask:0xf bank_mask:0xf\n\t" \
  /* c = sf*c + si*tg */ \
  "v_mul_f32 v180, v176, v179\n\t" \
  "v_fma_f32 v181, v177, v181, v180\n\t" \
  /* tanh(c) */ \
  "v_mul_f32 v182, s88, v181\n\t" \
  "v_exp_f32 v182, v182\n\t" \
  "s_nop 1\n\t" \
  "v_add_f32 v182, 1.0, v182\n\t" \
  "v_rcp_f32 v182, v182\n\t" \
  "s_nop 1\n\t" \
  "v_fma_f32 v182, v182, 2.0, -1.0\n\t" \
  "v_mul_f32 v183, v178, v182\n\t" \
  "v_cvt_f16_f32 v183, v183\n\t" \
  /* write h as f16 (kq==0 lanes) */ \
  "s_and_saveexec_b64 s[84:85], s[82:83]\n\t" \
  "ds_write_b16 %[wr], v183 offset:" #WOFF "\n\t" \
  "s_mov_b64 exec, s[84:85]\n\t" \
  "s_waitcnt lgkmcnt(0)\n\t" \
  "s_barrier\n\t"

__global__ __launch_bounds__(512, 2)
__attribute__((amdgpu_waves_per_eu(2, 2)))
void lstm_kernel(
    const float* __restrict__ A,      // (T,128,4)
    const float* __restrict__ W_hh,   // (512,128)
    const float* __restrict__ W_fc,   // (5,128)
    const float* __restrict__ b_fc,   // (5,)
    float* __restrict__ out)          // (5,)
{
    const int tid  = threadIdx.x;            // 0..511
    const int wave = tid >> 6;               // 0..7
    const int kq   = tid & 3;                // quad lane = K-chunk id = OWN GATE
    const int idx  = (tid >> 2) & 15;
    const int q    = wave * 16 + idx;        // h index 0..127
    const int kbase = kq * 32;               // K-chunk start (f32 elements)

    // h as f16: 2 buffers x 128 f16 = 2 x 256B; slot layout below
    __shared__ __align__(16) float h_s[2][64];

    if (tid < 128) ((float*)h_s)[tid] = 0.f;  // h_{-1} = 0 (both bufs, f16 0)
    __syncthreads();

    // per-thread addresses / constants for the asm block
    const unsigned long long wai = (unsigned long long)(uintptr_t)(W_hh + (size_t)q         * D_LSTM + kbase);
    const unsigned long long waf = (unsigned long long)(uintptr_t)(W_hh + (size_t)(128 + q) * D_LSTM + kbase);
    const unsigned long long wag = (unsigned long long)(uintptr_t)(W_hh + (size_t)(256 + q) * D_LSTM + kbase);
    const unsigned long long wao = (unsigned long long)(uintptr_t)(W_hh + (size_t)(384 + q) * D_LSTM + kbase);
    const unsigned int atid = (unsigned int)(q * 16 + kq * 4);   // byte off of own-gate scalar
    const unsigned int lds0 = (unsigned int)(uintptr_t)&h_s[0][0];
    const unsigned int rd   = lds0 + (unsigned int)(kq * 16);
    // write position: octet o=q>>3 at slot (o&3)*4+(o>>2), halfword q&7
    const int o  = q >> 3;
    const int sl = ((o & 3) << 2) | (o >> 2);
    const unsigned int wr = lds0 + (unsigned int)(sl * 16 + (q & 7) * 2);
    const unsigned long long wm  = __ballot(kq == 0);
    const unsigned long long mb0 = __ballot(kq & 1);
    const unsigned long long mb1 = __ballot(kq & 2);
    const float m1 = (kq == 2) ? -2.8853900817779268f  // -2*log2(e)
                               : -1.4426950408889634f; // -log2(e)
    const float sc = (kq == 2) ? 2.0f : 1.0f;
    const float ad = (kq == 2) ? -1.0f : 0.0f;

    asm volatile(
        // ---- prologue: consts; load f32 weight rows; pack to f16 v0-63 ----
        "s_mov_b32 s80, 2048\n\t"
        "s_mov_b32 s86, 4096\n\t"
        "s_mov_b32 s88, 0xC038AA3B\n\t"     // -2*log2(e)
        "s_mov_b64 s[82:83], %[wm]\n\t"
        ROWLOAD(wai)
        ROWPACK(0,1,2,3,4,5,6,7,8,9,10,11,12,13,14,15)
        ROWLOAD(waf)
        ROWPACK(16,17,18,19,20,21,22,23,24,25,26,27,28,29,30,31)
        ROWLOAD(wag)
        ROWPACK(32,33,34,35,36,37,38,39,40,41,42,43,44,45,46,47)
        ROWLOAD(wao)
        ROWPACK(48,49,50,51,52,53,54,55,56,57,58,59,60,61,62,63)
        "global_load_dword v168, %[at], %[ab]\n\t"   // A row 0 (own gate scalar)
        "s_waitcnt vmcnt(0)\n\t"
        "v_mov_b32 v181, 0\n\t"             // c = 0
        "1:\n\t"
        // even step: read buf0 (+0), consume v168, prefetch v172, write buf1 (+256)
        HALF(172, 168, 0,64,128,192, 256)
        // odd step: read buf1 (+256), consume v172, prefetch v168, write buf0 (+0)
        HALF(168, 172, 256,320,384,448, 0)
        "s_sub_u32 s86, s86, 1\n\t"
        "s_cmp_lg_u32 s86, 0\n\t"
        "s_cbranch_scc1 1b\n\t"
        :
        : [wai]"v"(wai), [waf]"v"(waf), [wag]"v"(wag), [wao]"v"(wao),
          [ab]"s"(A), [at]"v"(atid), [rd]"v"(rd), [wr]"v"(wr), [wm]"s"(wm),
          [mb0]"s"(mb0), [mb1]"s"(mb1), [m1]"v"(m1), [sc]"v"(sc), [ad]"v"(ad)
        : "v0","v1","v2","v3","v4","v5","v6","v7","v8","v9",
          "v10","v11","v12","v13","v14","v15","v16","v17","v18","v19",
          "v20","v21","v22","v23","v24","v25","v26","v27","v28","v29",
          "v30","v31","v32","v33","v34","v35","v36","v37","v38","v39",
          "v40","v41","v42","v43","v44","v45","v46","v47","v48","v49",
          "v50","v51","v52","v53","v54","v55","v56","v57","v58","v59",
          "v60","v61","v62","v63","v64","v65","v66","v67","v68","v69",
          "v70","v71","v72","v73","v74","v75","v76","v77","v78","v79",
          "v80","v81","v82","v83","v84","v85","v86","v87","v88","v89",
          "v90","v91","v92","v93","v94","v95","v96","v97","v98","v99",
          "v100","v101","v102","v103","v104","v105","v106","v107","v108","v109",
          "v110","v111","v112","v113","v114","v115","v116","v117","v118","v119",
          "v120","v121","v122","v123","v124","v125","v126","v127","v128","v129",
          "v130","v131","v132","v133","v134","v135","v136","v137","v138","v139",
          "v140","v141","v142","v143","v144","v145","v146","v147","v148","v149",
          "v150","v151","v152","v153","v154","v155","v156","v157","v158","v159",
          "v160","v161","v162","v163","v164","v165","v166","v167","v168","v169",
          "v170","v171","v172","v173","v174","v175","v176","v177","v178","v179",
          "v180","v181","v182","v183","v184","v185","v186","v187","v188","v189",
          "v190","v191",
          "s80","s81","s82","s83","s84","s85","s86","s87","s88",
          "scc","memory"
    );

    __syncthreads();

    // final FC: out = hT @ W_fc.T + b_fc  (final h in buffer 0, f16, slotted)
    if (tid < N_CLS) {
        const __half* hh = (const __half*)&h_s[0][0];
        float acc = b_fc[tid];
        #pragma unroll
        for (int k = 0; k < D_LSTM; ++k) {
            const int o2  = k >> 3;
            const int sl2 = ((o2 & 3) << 2) | (o2 >> 2);
            acc += __half2float(hh[sl2 * 8 + (k & 7)]) * W_fc[tid * D_LSTM + k];
        }
        out[tid] = acc;
    }
}

// ---------------------------------------------------------------------------
extern "C" void kernel_launch(void* const* d_in, const int* in_sizes, int n_in,
                              void* d_out, int out_size, void* d_ws, size_t ws_size,
                              hipStream_t stream) {
    const float* x       = (const float*)d_in[0];
    const int*   esrc    = (const int*)  d_in[1];
    const int*   edst    = (const int*)  d_in[2];
    const float* W_rel1  = (const float*)d_in[3];
    const float* b_rel1  = (const float*)d_in[4];
    const float* W_root1 = (const float*)d_in[5];
    const float* W_rel2  = (const float*)d_in[6];
    const float* b_rel2  = (const float*)d_in[7];
    const float* W_root2 = (const float*)d_in[8];
    const float* W_ih    = (const float*)d_in[9];
    const float* W_hh    = (const float*)d_in[10];
    const float* b_ih    = (const float*)d_in[11];
    const float* b_hh    = (const float*)d_in[12];
    const float* W_fc    = (const float*)d_in[13];
    const float* b_fc    = (const float*)d_in[14];

    float* out = (float*)d_out;
    float* A   = (float*)d_ws;   // (T,128,4) f32 = 16 MB

    gnn_proj_kernel<<<T_LEN / TB, 64, 0, stream>>>(
        x, esrc, edst, W_rel1, b_rel1, W_root1,
        W_rel2, b_rel2, W_root2, W_ih, b_ih, b_hh, A);

    lstm_kernel<<<1, 512, 0, stream>>>(A, W_hh, W_fc, b_fc, out);
}

// Round 16
// 4379.944 us; speedup vs baseline: 1.1144x; 1.1144x over previous
//
#include <hip/hip_runtime.h>
#include <hip/hip_fp16.h>

#define T_LEN 8192
#define N_NODES 33
#define N_EDGES 64
#define DIM_IN 3
#define D_H 64
#define D_LSTM 128
#define N_CLS 5
#define TB 4   // timesteps per block in kernel 1

typedef float v2f __attribute__((ext_vector_type(2)));
typedef float v4f __attribute__((ext_vector_type(4)));

// ---------------------------------------------------------------------------
// Kernel 1: graph conv x2 + relu + mean over nodes + input-side LSTM projection
// Writes A in (T, 128, 4) layout: A[(t*128+q)*4 + g] = gate g of unit q
// (g: 0=i, 1=f, 2=g, 3=o).  LSTM thread (q,kq) scalar-loads its own gate.
// ---------------------------------------------------------------------------
__global__ __launch_bounds__(64, 2) void gnn_proj_kernel(
    const float* __restrict__ x,        // (T,33,3)
    const int*   __restrict__ esrc,     // (64,)
    const int*   __restrict__ edst,     // (64,)
    const float* __restrict__ W_rel1,   // (64,3)
    const float* __restrict__ b_rel1,   // (64,)
    const float* __restrict__ W_root1,  // (64,3)
    const float* __restrict__ W_rel2,   // (64,64)
    const float* __restrict__ b_rel2,   // (64,)
    const float* __restrict__ W_root2,  // (64,64)
    const float* __restrict__ W_ih,     // (512,64)
    const float* __restrict__ b_ih,     // (512,)
    const float* __restrict__ b_hh,     // (512,)
    float* __restrict__ A)              // (T,128,4)  [workspace]
{
    const int t0 = blockIdx.x * TB;
    const int j  = threadIdx.x;   // 0..63

    __shared__ __align__(16) float x_s[N_NODES][DIM_IN];
    __shared__ __align__(16) float agg1[N_NODES][DIM_IN];
    __shared__ __align__(16) float h1[N_NODES][D_H];
    __shared__ __align__(16) float agg2[N_NODES][D_H];
    __shared__ __align__(16) float seq_s[TB][D_H];
    __shared__ int es[N_EDGES], ed[N_EDGES];

    es[j] = esrc[j];
    ed[j] = edst[j];

    const float wr1_0 = W_rel1[j*3+0], wr1_1 = W_rel1[j*3+1], wr1_2 = W_rel1[j*3+2];
    const float wt1_0 = W_root1[j*3+0], wt1_1 = W_root1[j*3+1], wt1_2 = W_root1[j*3+2];
    const float br1 = b_rel1[j];
    const float br2 = b_rel2[j];

    float wr2[D_H], wt2[D_H];
    #pragma unroll
    for (int k = 0; k < D_H; ++k) {
        wr2[k] = W_rel2[j*D_H + k];
        wt2[k] = W_root2[j*D_H + k];
    }

    for (int tt = 0; tt < TB; ++tt) {
        const int t = t0 + tt;
        __syncthreads();

        const float* xt = x + (size_t)t * (N_NODES * DIM_IN);
        for (int i = j; i < N_NODES * DIM_IN; i += 64) x_s[0][i] = xt[i];
        __syncthreads();

        if (j < N_NODES) {
            float a0 = 0.f, a1 = 0.f, a2 = 0.f;
            for (int e = 0; e < N_EDGES; ++e) {
                if (ed[e] == j) {
                    a0 += x_s[es[e]][0];
                    a1 += x_s[es[e]][1];
                    a2 += x_s[es[e]][2];
                }
            }
            agg1[j][0] = a0; agg1[j][1] = a1; agg1[j][2] = a2;
        }
        __syncthreads();

        for (int n = 0; n < N_NODES; ++n) {
            float v = br1
                + agg1[n][0]*wr1_0 + agg1[n][1]*wr1_1 + agg1[n][2]*wr1_2
                + x_s[n][0]*wt1_0  + x_s[n][1]*wt1_1  + x_s[n][2]*wt1_2;
            h1[n][j]  = v;
            agg2[n][j] = 0.f;
        }
        __syncthreads();

        for (int e = 0; e < N_EDGES; ++e) {
            agg2[ed[e]][j] += h1[es[e]][j];
        }
        __syncthreads();

        float seqv = 0.f;
        for (int n = 0; n < N_NODES; ++n) {
            const float4* ag4 = (const float4*)agg2[n];
            const float4* h4  = (const float4*)h1[n];
            float acc0 = br2, acc1 = 0.f, acc2 = 0.f, acc3 = 0.f;
            #pragma unroll
            for (int k4 = 0; k4 < D_H/4; ++k4) {
                float4 av = ag4[k4];
                float4 hv = h4[k4];
                acc0 += av.x * wr2[4*k4+0] + hv.x * wt2[4*k4+0];
                acc1 += av.y * wr2[4*k4+1] + hv.y * wt2[4*k4+1];
                acc2 += av.z * wr2[4*k4+2] + hv.z * wt2[4*k4+2];
                acc3 += av.w * wr2[4*k4+3] + hv.w * wt2[4*k4+3];
            }
            float acc = (acc0 + acc1) + (acc2 + acc3);
            seqv += fmaxf(acc, 0.f);
        }
        seq_s[tt][j] = seqv * (1.0f / 33.0f);
    }
    __syncthreads();

    #pragma unroll
    for (int m = 0; m < 8; ++m) {
        const int o = m * 64 + j;
        const float bias = b_ih[o] + b_hh[o];
        const float4* w4 = (const float4*)(W_ih + (size_t)o * D_H);
        float acc[TB];
        #pragma unroll
        for (int tt = 0; tt < TB; ++tt) acc[tt] = bias;
        #pragma unroll
        for (int k4 = 0; k4 < D_H/4; ++k4) {
            float4 wv = w4[k4];
            #pragma unroll
            for (int tt = 0; tt < TB; ++tt) {
                const float4* s4 = (const float4*)seq_s[tt];
                float4 sv = s4[k4];
                acc[tt] += sv.x*wv.x + sv.y*wv.y + sv.z*wv.z + sv.w*wv.w;
            }
        }
        // (T,128,4) layout: q = o&127, g = o>>7
        #pragma unroll
        for (int tt = 0; tt < TB; ++tt) {
            A[((size_t)(t0 + tt) * 128 + (o & 127)) * 4 + (o >> 7)] = acc[tt];
        }
    }
}

// ---------------------------------------------------------------------------
// Kernel 2 (round 16 = round 14 proven structure + latency-hiding order):
//  - MAC = v_dot2_f32_f16 with f32 accumulate (r14's best: 4102 us; r15's
//    pk_fma_f16 regressed - all MAC encodings issue at 4 cyc/wave, the VALU
//    floor is 512 cyc/step; only overhead is attackable).
//  - ds_reads issued FIRST after the barrier (critical path), A-prefetch and
//    SALU wrap logic moved into the read-latency shadow.
//  - fine lgkmcnt(3/2/1/0) staging: 16 MACs (~64cyc) cover each later read.
//  - everything else byte-identical to r14 (DPP reduce-scatter, per-lane
//    nonlin, scalar A, f16 h exchange, 1 barrier/step).
// Register map: v0-63 packed f16 weights | v128-143 h (f16 dwords) |
// v160-163 accs | v168/v172 A dbuf | v176-190 temps | v181 c.
// ---------------------------------------------------------------------------

#define CVTPK(D,S0,S1) \
  "v_cvt_f16_f32 v190, v" #S0 "\n\t" \
  "v_cvt_f16_f32 v191, v" #S1 "\n\t" \
  "v_and_b32 v190, 0xffff, v190\n\t" \
  "v_lshlrev_b32 v191, 16, v191\n\t" \
  "v_or_b32 v" #D ", v190, v191\n\t"

#define ROWPACK(D0,D1,D2,D3,D4,D5,D6,D7,D8,D9,D10,D11,D12,D13,D14,D15) \
  CVTPK(D0,128,129) CVTPK(D1,130,131) CVTPK(D2,132,133) CVTPK(D3,134,135) \
  CVTPK(D4,136,137) CVTPK(D5,138,139) CVTPK(D6,140,141) CVTPK(D7,142,143) \
  CVTPK(D8,144,145) CVTPK(D9,146,147) CVTPK(D10,148,149) CVTPK(D11,150,151) \
  CVTPK(D12,152,153) CVTPK(D13,154,155) CVTPK(D14,156,157) CVTPK(D15,158,159)

#define ROWLOAD(WA) \
  "global_load_dwordx4 v[128:131], %[" #WA "], off\n\t" \
  "global_load_dwordx4 v[132:135], %[" #WA "], off offset:16\n\t" \
  "global_load_dwordx4 v[136:139], %[" #WA "], off offset:32\n\t" \
  "global_load_dwordx4 v[140:143], %[" #WA "], off offset:48\n\t" \
  "global_load_dwordx4 v[144:147], %[" #WA "], off offset:64\n\t" \
  "global_load_dwordx4 v[148:151], %[" #WA "], off offset:80\n\t" \
  "global_load_dwordx4 v[152:155], %[" #WA "], off offset:96\n\t" \
  "global_load_dwordx4 v[156:159], %[" #WA "], off offset:112\n\t" \
  "s_waitcnt vmcnt(0)\n\t"

// 4 dot2 (one per gate) for h dword H against weight dwords A,B,C,D
#define DOT4(H, A,B,C,D) \
  "v_dot2_f32_f16 v160, v" #H ", v" #A ", v160\n\t" \
  "v_dot2_f32_f16 v161, v" #H ", v" #B ", v161\n\t" \
  "v_dot2_f32_f16 v162, v" #H ", v" #C ", v162\n\t" \
  "v_dot2_f32_f16 v163, v" #H ", v" #D ", v163\n\t"
#define DOT4Z(H, A,B,C,D) \
  "v_dot2_f32_f16 v160, v" #H ", v" #A ", 0\n\t" \
  "v_dot2_f32_f16 v161, v" #H ", v" #B ", 0\n\t" \
  "v_dot2_f32_f16 v162, v" #H ", v" #C ", 0\n\t" \
  "v_dot2_f32_f16 v163, v" #H ", v" #D ", 0\n\t"

// P = prefetch dest reg (next step's A), PC = consume reg (this step's A)
#define HALF(P, PC, R0,R1,R2,R3, WOFF) \
  "ds_read_b128 v[128:131], %[rd] offset:" #R0 "\n\t" \
  "ds_read_b128 v[132:135], %[rd] offset:" #R1 "\n\t" \
  "ds_read_b128 v[136:139], %[rd] offset:" #R2 "\n\t" \
  "ds_read_b128 v[140:143], %[rd] offset:" #R3 "\n\t" \
  "v_add_u32 v190, s80, %[at]\n\t" \
  "global_load_dword v" #P ", v190, %[ab]\n\t" \
  "s_add_u32 s80, s80, 2048\n\t" \
  "s_cmp_lg_u32 s80, 0x1000000\n\t" \
  "s_cselect_b32 s80, s80, 0\n\t" \
  "s_waitcnt lgkmcnt(3)\n\t" \
  DOT4Z(128, 0,16,32,48) \
  DOT4(129, 1,17,33,49) \
  DOT4(130, 2,18,34,50) \
  DOT4(131, 3,19,35,51) \
  "s_waitcnt lgkmcnt(2)\n\t" \
  DOT4(132, 4,20,36,52) \
  DOT4(133, 5,21,37,53) \
  DOT4(134, 6,22,38,54) \
  DOT4(135, 7,23,39,55) \
  "s_waitcnt lgkmcnt(1)\n\t" \
  DOT4(136, 8,24,40,56) \
  DOT4(137, 9,25,41,57) \
  DOT4(138, 10,26,42,58) \
  DOT4(139, 11,27,43,59) \
  "s_waitcnt lgkmcnt(0)\n\t" \
  DOT4(140, 12,28,44,60) \
  DOT4(141, 13,29,45,61) \
  DOT4(142, 14,30,46,62) \
  DOT4(143, 15,31,47,63) \
  /* quad reduce-scatter: accs v160=i v161=f v162=g v163=o */ \
  "v_mov_b32_dpp v184, v160 quad_perm:[2,3,0,1] row_mask:0xf bank_mask:0xf\n\t" \
  "v_mov_b32_dpp v185, v161 quad_perm:[2,3,0,1] row_mask:0xf bank_mask:0xf\n\t" \
  "v_mov_b32_dpp v186, v162 quad_perm:[2,3,0,1] row_mask:0xf bank_mask:0xf\n\t" \
  "v_mov_b32_dpp v187, v163 quad_perm:[2,3,0,1] row_mask:0xf bank_mask:0xf\n\t" \
  "v_add_f32 v160, v160, v184\n\t" \
  "v_add_f32 v161, v161, v185\n\t" \
  "v_add_f32 v162, v162, v186\n\t" \
  "v_add_f32 v163, v163, v187\n\t" \
  "v_cndmask_b32 v184, v160, v162, %[mb1]\n\t" \
  "v_cndmask_b32 v185, v161, v163, %[mb1]\n\t" \
  "s_nop 1\n\t" \
  "v_mov_b32_dpp v186, v184 quad_perm:[1,0,3,2] row_mask:0xf bank_mask:0xf\n\t" \
  "v_mov_b32_dpp v187, v185 quad_perm:[1,0,3,2] row_mask:0xf bank_mask:0xf\n\t" \
  "v_add_f32 v184, v184, v186\n\t" \
  "v_add_f32 v185, v185, v187\n\t" \
  "v_cndmask_b32 v184, v184, v185, %[mb0]\n\t"   /* lane kq: sum of gate kq */ \
  "s_waitcnt vmcnt(1)\n\t" \
  "v_add_f32 v184, v184, v" #PC "\n\t" \
  /* per-lane nonlin: y=rcp(1+exp2(m1*x)); y'=y*sc+ad */ \
  "v_mul_f32 v186, %[m1], v184\n\t" \
  "v_exp_f32 v186, v186\n\t" \
  "s_nop 1\n\t" \
  "v_add_f32 v186, 1.0, v186\n\t" \
  "v_rcp_f32 v186, v186\n\t" \
  "s_nop 1\n\t" \
  "v_fma_f32 v186, v186, %[sc], %[ad]\n\t" \
  "s_nop 1\n\t" \
  /* quad broadcast: si,sf,tg,so */ \
  "v_mov_b32_dpp v176, v186 quad_perm:[0,0,0,0] row_mask:0xf bank_mask:0xf\n\t" \
  "v_mov_b32_dpp v177, v186 quad_perm:[1,1,1,1] row_mask:0xf bank_mask:0xf\n\t" \
  "v_mov_b32_dpp v179, v186 quad_perm:[2,2,2,2] row_mask:0xf bank_mask:0xf\n\t" \
  "v_mov_b32_dpp v178, v186 quad_perm:[3,3,3,3] row_mask:0xf bank_mask:0xf\n\t" \
  /* c = sf*c + si*tg */ \
  "v_mul_f32 v180, v176, v179\n\t" \
  "v_fma_f32 v181, v177, v181, v180\n\t" \
  /* tanh(c) */ \
  "v_mul_f32 v182, s88, v181\n\t" \
  "v_exp_f32 v182, v182\n\t" \
  "s_nop 1\n\t" \
  "v_add_f32 v182, 1.0, v182\n\t" \
  "v_rcp_f32 v182, v182\n\t" \
  "s_nop 1\n\t" \
  "v_fma_f32 v182, v182, 2.0, -1.0\n\t" \
  "v_mul_f32 v183, v178, v182\n\t" \
  "v_cvt_f16_f32 v183, v183\n\t" \
  /* write h as f16 (kq==0 lanes) */ \
  "s_and_saveexec_b64 s[84:85], s[82:83]\n\t" \
  "ds_write_b16 %[wr], v183 offset:" #WOFF "\n\t" \
  "s_mov_b64 exec, s[84:85]\n\t" \
  "s_waitcnt lgkmcnt(0)\n\t" \
  "s_barrier\n\t"

__global__ __launch_bounds__(512, 2)
__attribute__((amdgpu_waves_per_eu(2, 2)))
void lstm_kernel(
    const float* __restrict__ A,      // (T,128,4)
    const float* __restrict__ W_hh,   // (512,128)
    const float* __restrict__ W_fc,   // (5,128)
    const float* __restrict__ b_fc,   // (5,)
    float* __restrict__ out)          // (5,)
{
    const int tid  = threadIdx.x;            // 0..511
    const int wave = tid >> 6;               // 0..7
    const int kq   = tid & 3;                // quad lane = K-chunk id = OWN GATE
    const int idx  = (tid >> 2) & 15;
    const int q    = wave * 16 + idx;        // h index 0..127
    const int kbase = kq * 32;               // K-chunk start (f32 elements)

    // h as f16: 2 buffers x 128 f16 = 2 x 256B; slot layout below
    __shared__ __align__(16) float h_s[2][64];

    if (tid < 128) ((float*)h_s)[tid] = 0.f;  // h_{-1} = 0 (both bufs, f16 0)
    __syncthreads();

    // per-thread addresses / constants for the asm block
    const unsigned long long wai = (unsigned long long)(uintptr_t)(W_hh + (size_t)q         * D_LSTM + kbase);
    const unsigned long long waf = (unsigned long long)(uintptr_t)(W_hh + (size_t)(128 + q) * D_LSTM + kbase);
    const unsigned long long wag = (unsigned long long)(uintptr_t)(W_hh + (size_t)(256 + q) * D_LSTM + kbase);
    const unsigned long long wao = (unsigned long long)(uintptr_t)(W_hh + (size_t)(384 + q) * D_LSTM + kbase);
    const unsigned int atid = (unsigned int)(q * 16 + kq * 4);   // byte off of own-gate scalar
    const unsigned int lds0 = (unsigned int)(uintptr_t)&h_s[0][0];
    const unsigned int rd   = lds0 + (unsigned int)(kq * 16);
    // write position: octet o=q>>3 at slot (o&3)*4+(o>>2), halfword q&7
    const int o  = q >> 3;
    const int sl = ((o & 3) << 2) | (o >> 2);
    const unsigned int wr = lds0 + (unsigned int)(sl * 16 + (q & 7) * 2);
    const unsigned long long wm  = __ballot(kq == 0);
    const unsigned long long mb0 = __ballot(kq & 1);
    const unsigned long long mb1 = __ballot(kq & 2);
    const float m1 = (kq == 2) ? -2.8853900817779268f  // -2*log2(e)
                               : -1.4426950408889634f; // -log2(e)
    const float sc = (kq == 2) ? 2.0f : 1.0f;
    const float ad = (kq == 2) ? -1.0f : 0.0f;

    asm volatile(
        // ---- prologue: consts; load f32 weight rows; pack to f16 v0-63 ----
        "s_mov_b32 s80, 2048\n\t"
        "s_mov_b32 s86, 4096\n\t"
        "s_mov_b32 s88, 0xC038AA3B\n\t"     // -2*log2(e)
        "s_mov_b64 s[82:83], %[wm]\n\t"
        ROWLOAD(wai)
        ROWPACK(0,1,2,3,4,5,6,7,8,9,10,11,12,13,14,15)
        ROWLOAD(waf)
        ROWPACK(16,17,18,19,20,21,22,23,24,25,26,27,28,29,30,31)
        ROWLOAD(wag)
        ROWPACK(32,33,34,35,36,37,38,39,40,41,42,43,44,45,46,47)
        ROWLOAD(wao)
        ROWPACK(48,49,50,51,52,53,54,55,56,57,58,59,60,61,62,63)
        "global_load_dword v168, %[at], %[ab]\n\t"   // A row 0 (own gate scalar)
        "s_waitcnt vmcnt(0)\n\t"
        "v_mov_b32 v181, 0\n\t"             // c = 0
        "1:\n\t"
        // even step: read buf0 (+0), consume v168, prefetch v172, write buf1 (+256)
        HALF(172, 168, 0,64,128,192, 256)
        // odd step: read buf1 (+256), consume v172, prefetch v168, write buf0 (+0)
        HALF(168, 172, 256,320,384,448, 0)
        "s_sub_u32 s86, s86, 1\n\t"
        "s_cmp_lg_u32 s86, 0\n\t"
        "s_cbranch_scc1 1b\n\t"
        :
        : [wai]"v"(wai), [waf]"v"(waf), [wag]"v"(wag), [wao]"v"(wao),
          [ab]"s"(A), [at]"v"(atid), [rd]"v"(rd), [wr]"v"(wr), [wm]"s"(wm),
          [mb0]"s"(mb0), [mb1]"s"(mb1), [m1]"v"(m1), [sc]"v"(sc), [ad]"v"(ad)
        : "v0","v1","v2","v3","v4","v5","v6","v7","v8","v9",
          "v10","v11","v12","v13","v14","v15","v16","v17","v18","v19",
          "v20","v21","v22","v23","v24","v25","v26","v27","v28","v29",
          "v30","v31","v32","v33","v34","v35","v36","v37","v38","v39",
          "v40","v41","v42","v43","v44","v45","v46","v47","v48","v49",
          "v50","v51","v52","v53","v54","v55","v56","v57","v58","v59",
          "v60","v61","v62","v63","v64","v65","v66","v67","v68","v69",
          "v70","v71","v72","v73","v74","v75","v76","v77","v78","v79",
          "v80","v81","v82","v83","v84","v85","v86","v87","v88","v89",
          "v90","v91","v92","v93","v94","v95","v96","v97","v98","v99",
          "v100","v101","v102","v103","v104","v105","v106","v107","v108","v109",
          "v110","v111","v112","v113","v114","v115","v116","v117","v118","v119",
          "v120","v121","v122","v123","v124","v125","v126","v127","v128","v129",
          "v130","v131","v132","v133","v134","v135","v136","v137","v138","v139",
          "v140","v141","v142","v143","v144","v145","v146","v147","v148","v149",
          "v150","v151","v152","v153","v154","v155","v156","v157","v158","v159",
          "v160","v161","v162","v163","v164","v165","v166","v167","v168","v169",
          "v170","v171","v172","v173","v174","v175","v176","v177","v178","v179",
          "v180","v181","v182","v183","v184","v185","v186","v187","v188","v189",
          "v190","v191",
          "s80","s81","s82","s83","s84","s85","s86","s87","s88",
          "scc","memory"
    );

    __syncthreads();

    // final FC: out = hT @ W_fc.T + b_fc  (final h in buffer 0, f16, slotted)
    if (tid < N_CLS) {
        const __half* hh = (const __half*)&h_s[0][0];
        float acc = b_fc[tid];
        #pragma unroll
        for (int k = 0; k < D_LSTM; ++k) {
            const int o2  = k >> 3;
            const int sl2 = ((o2 & 3) << 2) | (o2 >> 2);
            acc += __half2float(hh[sl2 * 8 + (k & 7)]) * W_fc[tid * D_LSTM + k];
        }
        out[tid] = acc;
    }
}

// ---------------------------------------------------------------------------
extern "C" void kernel_launch(void* const* d_in, const int* in_sizes, int n_in,
                              void* d_out, int out_size, void* d_ws, size_t ws_size,
                              hipStream_t stream) {
    const float* x       = (const float*)d_in[0];
    const int*   esrc    = (const int*)  d_in[1];
    const int*   edst    = (const int*)  d_in[2];
    const float* W_rel1  = (const float*)d_in[3];
    const float* b_rel1  = (const float*)d_in[4];
    const float* W_root1 = (const float*)d_in[5];
    const float* W_rel2  = (const float*)d_in[6];
    const float* b_rel2  = (const float*)d_in[7];
    const float* W_root2 = (const float*)d_in[8];
    const float* W_ih    = (const float*)d_in[9];
    const float* W_hh    = (const float*)d_in[10];
    const float* b_ih    = (const float*)d_in[11];
    const float* b_hh    = (const float*)d_in[12];
    const float* W_fc    = (const float*)d_in[13];
    const float* b_fc    = (const float*)d_in[14];

    float* out = (float*)d_out;
    float* A   = (float*)d_ws;   // (T,128,4) f32 = 16 MB

    gnn_proj_kernel<<<T_LEN / TB, 64, 0, stream>>>(
        x, esrc, edst, W_rel1, b_rel1, W_root1,
        W_rel2, b_rel2, W_root2, W_ih, b_ih, b_hh, A);

    lstm_kernel<<<1, 512, 0, stream>>>(A, W_hh, W_fc, b_fc, out);
}

// Round 18
// 3875.703 us; speedup vs baseline: 1.2593x; 1.1301x over previous
//
#include <hip/hip_runtime.h>
#include <hip/hip_fp16.h>

#define T_LEN 8192
#define N_NODES 33
#define N_EDGES 64
#define DIM_IN 3
#define D_H 64
#define D_LSTM 128
#define N_CLS 5
#define TB 4   // timesteps per block in kernel 1

typedef float v2f __attribute__((ext_vector_type(2)));
typedef float v4f __attribute__((ext_vector_type(4)));

// ---------------------------------------------------------------------------
// Kernel 1: graph conv x2 + relu + mean over nodes + input-side LSTM projection
// Writes A in (T, 128, 4) layout: A[(t*128+q)*4 + g] = gate g of unit q
// (g: 0=i, 1=f, 2=g, 3=o).  LSTM lane loads its unit's 4 gates as one dwordx4.
// ---------------------------------------------------------------------------
__global__ __launch_bounds__(64, 2) void gnn_proj_kernel(
    const float* __restrict__ x,        // (T,33,3)
    const int*   __restrict__ esrc,     // (64,)
    const int*   __restrict__ edst,     // (64,)
    const float* __restrict__ W_rel1,   // (64,3)
    const float* __restrict__ b_rel1,   // (64,)
    const float* __restrict__ W_root1,  // (64,3)
    const float* __restrict__ W_rel2,   // (64,64)
    const float* __restrict__ b_rel2,   // (64,)
    const float* __restrict__ W_root2,  // (64,64)
    const float* __restrict__ W_ih,     // (512,64)
    const float* __restrict__ b_ih,     // (512,)
    const float* __restrict__ b_hh,     // (512,)
    float* __restrict__ A)              // (T,128,4)  [workspace]
{
    const int t0 = blockIdx.x * TB;
    const int j  = threadIdx.x;   // 0..63

    __shared__ __align__(16) float x_s[N_NODES][DIM_IN];
    __shared__ __align__(16) float agg1[N_NODES][DIM_IN];
    __shared__ __align__(16) float h1[N_NODES][D_H];
    __shared__ __align__(16) float agg2[N_NODES][D_H];
    __shared__ __align__(16) float seq_s[TB][D_H];
    __shared__ int es[N_EDGES], ed[N_EDGES];

    es[j] = esrc[j];
    ed[j] = edst[j];

    const float wr1_0 = W_rel1[j*3+0], wr1_1 = W_rel1[j*3+1], wr1_2 = W_rel1[j*3+2];
    const float wt1_0 = W_root1[j*3+0], wt1_1 = W_root1[j*3+1], wt1_2 = W_root1[j*3+2];
    const float br1 = b_rel1[j];
    const float br2 = b_rel2[j];

    float wr2[D_H], wt2[D_H];
    #pragma unroll
    for (int k = 0; k < D_H; ++k) {
        wr2[k] = W_rel2[j*D_H + k];
        wt2[k] = W_root2[j*D_H + k];
    }

    for (int tt = 0; tt < TB; ++tt) {
        const int t = t0 + tt;
        __syncthreads();

        const float* xt = x + (size_t)t * (N_NODES * DIM_IN);
        for (int i = j; i < N_NODES * DIM_IN; i += 64) x_s[0][i] = xt[i];
        __syncthreads();

        if (j < N_NODES) {
            float a0 = 0.f, a1 = 0.f, a2 = 0.f;
            for (int e = 0; e < N_EDGES; ++e) {
                if (ed[e] == j) {
                    a0 += x_s[es[e]][0];
                    a1 += x_s[es[e]][1];
                    a2 += x_s[es[e]][2];
                }
            }
            agg1[j][0] = a0; agg1[j][1] = a1; agg1[j][2] = a2;
        }
        __syncthreads();

        for (int n = 0; n < N_NODES; ++n) {
            float v = br1
                + agg1[n][0]*wr1_0 + agg1[n][1]*wr1_1 + agg1[n][2]*wr1_2
                + x_s[n][0]*wt1_0  + x_s[n][1]*wt1_1  + x_s[n][2]*wt1_2;
            h1[n][j]  = v;
            agg2[n][j] = 0.f;
        }
        __syncthreads();

        for (int e = 0; e < N_EDGES; ++e) {
            agg2[ed[e]][j] += h1[es[e]][j];
        }
        __syncthreads();

        float seqv = 0.f;
        for (int n = 0; n < N_NODES; ++n) {
            const float4* ag4 = (const float4*)agg2[n];
            const float4* h4  = (const float4*)h1[n];
            float acc0 = br2, acc1 = 0.f, acc2 = 0.f, acc3 = 0.f;
            #pragma unroll
            for (int k4 = 0; k4 < D_H/4; ++k4) {
                float4 av = ag4[k4];
                float4 hv = h4[k4];
                acc0 += av.x * wr2[4*k4+0] + hv.x * wt2[4*k4+0];
                acc1 += av.y * wr2[4*k4+1] + hv.y * wt2[4*k4+1];
                acc2 += av.z * wr2[4*k4+2] + hv.z * wt2[4*k4+2];
                acc3 += av.w * wr2[4*k4+3] + hv.w * wt2[4*k4+3];
            }
            float acc = (acc0 + acc1) + (acc2 + acc3);
            seqv += fmaxf(acc, 0.f);
        }
        seq_s[tt][j] = seqv * (1.0f / 33.0f);
    }
    __syncthreads();

    #pragma unroll
    for (int m = 0; m < 8; ++m) {
        const int o = m * 64 + j;
        const float bias = b_ih[o] + b_hh[o];
        const float4* w4 = (const float4*)(W_ih + (size_t)o * D_H);
        float acc[TB];
        #pragma unroll
        for (int tt = 0; tt < TB; ++tt) acc[tt] = bias;
        #pragma unroll
        for (int k4 = 0; k4 < D_H/4; ++k4) {
            float4 wv = w4[k4];
            #pragma unroll
            for (int tt = 0; tt < TB; ++tt) {
                const float4* s4 = (const float4*)seq_s[tt];
                float4 sv = s4[k4];
                acc[tt] += sv.x*wv.x + sv.y*wv.y + sv.z*wv.z + sv.w*wv.w;
            }
        }
        // (T,128,4) layout: q = o&127, g = o>>7
        #pragma unroll
        for (int tt = 0; tt < TB; ++tt) {
            A[((size_t)(t0 + tt) * 128 + (o & 127)) * 4 + (o >> 7)] = acc[tt];
        }
    }
}

// ---------------------------------------------------------------------------
// Kernel 2 (round 18 = round 17 with the FRAGLOAD offset fix): MFMA LSTM.
// r17 bug: K-chunk kt lives at byte offset kt*128 (32 f32 columns), but the
// loads used kt*512 (= rows +1/+2/+3, wrong weights) -> absmax 0.249.
// Fixed offsets: 0/16, 128/144, 256/272, 384/400.
//
// 8 waves; wave w owns units q0=16w..q0+15.  Per step: gates = W_hh (4 gate
// tiles of 16 rows) @ h via 16 chained v_mfma_f32_16x16x32_f16.  B = h
// broadcast into all 16 cols -> every D col equals the gate vector -> all 64
// lanes hold valid gates at rows 4*(l>>4)+r (m89-verified D layout).  Lane
// selects r=l&3 (2-stage cndmask) -> one unit's 4 gates -> full nonlin
// (r11-proven) -> ds_write_b16 from 16 lanes; 1 barrier/step.
// Regs: v0-63 W-frags | v64-79 B-frags | v80-95 D | v164-167 zeros(C) |
// v168-175 A dbuf | v176-191 temps | v190 c.
// ---------------------------------------------------------------------------

#define CVTPK(D,S0,S1) \
  "v_cvt_f16_f32 v190, v" #S0 "\n\t" \
  "v_cvt_f16_f32 v191, v" #S1 "\n\t" \
  "v_and_b32 v190, 0xffff, v190\n\t" \
  "v_lshlrev_b32 v191, 16, v191\n\t" \
  "v_or_b32 v" #D ", v190, v191\n\t"

#define ROWPACK(D0,D1,D2,D3,D4,D5,D6,D7,D8,D9,D10,D11,D12,D13,D14,D15) \
  CVTPK(D0,128,129) CVTPK(D1,130,131) CVTPK(D2,132,133) CVTPK(D3,134,135) \
  CVTPK(D4,136,137) CVTPK(D5,138,139) CVTPK(D6,140,141) CVTPK(D7,142,143) \
  CVTPK(D8,144,145) CVTPK(D9,146,147) CVTPK(D10,148,149) CVTPK(D11,150,151) \
  CVTPK(D12,152,153) CVTPK(D13,154,155) CVTPK(D14,156,157) CVTPK(D15,158,159)

// fragment loads: 8 f32 per K-chunk kt at byte offsets kt*128 (32 f32 cols)
#define FRAGLOAD(WA) \
  "global_load_dwordx4 v[128:131], %[" #WA "], off\n\t" \
  "global_load_dwordx4 v[132:135], %[" #WA "], off offset:16\n\t" \
  "global_load_dwordx4 v[136:139], %[" #WA "], off offset:128\n\t" \
  "global_load_dwordx4 v[140:143], %[" #WA "], off offset:144\n\t" \
  "global_load_dwordx4 v[144:147], %[" #WA "], off offset:256\n\t" \
  "global_load_dwordx4 v[148:151], %[" #WA "], off offset:272\n\t" \
  "global_load_dwordx4 v[152:155], %[" #WA "], off offset:384\n\t" \
  "global_load_dwordx4 v[156:159], %[" #WA "], off offset:400\n\t" \
  "s_waitcnt vmcnt(0)\n\t"

// P0:P3 = prefetch dest regs; PC0..PC3 = consume regs (this step's A biases)
#define HALF(P0,P3, PC0,PC1,PC2,PC3, R0,R1,R2,R3, WOFF) \
  "ds_read_b128 v[64:67], %[rb] offset:" #R0 "\n\t" \
  "ds_read_b128 v[68:71], %[rb] offset:" #R1 "\n\t" \
  "ds_read_b128 v[72:75], %[rb] offset:" #R2 "\n\t" \
  "ds_read_b128 v[76:79], %[rb] offset:" #R3 "\n\t" \
  "v_add_u32 v189, s80, %[at]\n\t" \
  "global_load_dwordx4 v[" #P0 ":" #P3 "], v189, %[ab]\n\t" \
  "s_add_u32 s80, s80, 2048\n\t" \
  "s_cmp_lg_u32 s80, 0x1000000\n\t" \
  "s_cselect_b32 s80, s80, 0\n\t" \
  "s_waitcnt lgkmcnt(0)\n\t" \
  /* 16 mfma: 4 gate chains x 4 K-chunks, round-robin interleaved */ \
  "v_mfma_f32_16x16x32_f16 v[80:83], v[0:3],   v[64:67], v[164:167]\n\t" \
  "v_mfma_f32_16x16x32_f16 v[84:87], v[16:19], v[64:67], v[164:167]\n\t" \
  "v_mfma_f32_16x16x32_f16 v[88:91], v[32:35], v[64:67], v[164:167]\n\t" \
  "v_mfma_f32_16x16x32_f16 v[92:95], v[48:51], v[64:67], v[164:167]\n\t" \
  "v_mfma_f32_16x16x32_f16 v[80:83], v[4:7],   v[68:71], v[80:83]\n\t" \
  "v_mfma_f32_16x16x32_f16 v[84:87], v[20:23], v[68:71], v[84:87]\n\t" \
  "v_mfma_f32_16x16x32_f16 v[88:91], v[36:39], v[68:71], v[88:91]\n\t" \
  "v_mfma_f32_16x16x32_f16 v[92:95], v[52:55], v[68:71], v[92:95]\n\t" \
  "v_mfma_f32_16x16x32_f16 v[80:83], v[8:11],  v[72:75], v[80:83]\n\t" \
  "v_mfma_f32_16x16x32_f16 v[84:87], v[24:27], v[72:75], v[84:87]\n\t" \
  "v_mfma_f32_16x16x32_f16 v[88:91], v[40:43], v[72:75], v[88:91]\n\t" \
  "v_mfma_f32_16x16x32_f16 v[92:95], v[56:59], v[72:75], v[92:95]\n\t" \
  "v_mfma_f32_16x16x32_f16 v[80:83], v[12:15], v[76:79], v[80:83]\n\t" \
  "v_mfma_f32_16x16x32_f16 v[84:87], v[28:31], v[76:79], v[84:87]\n\t" \
  "v_mfma_f32_16x16x32_f16 v[88:91], v[44:47], v[76:79], v[88:91]\n\t" \
  "v_mfma_f32_16x16x32_f16 v[92:95], v[60:63], v[76:79], v[92:95]\n\t" \
  "s_nop 7\n\t" \
  "s_nop 7\n\t" \
  /* D-select r = lane&3 (2-stage cndmask), per gate */ \
  "v_cndmask_b32 v184, v80, v82, %[sb1]\n\t" \
  "v_cndmask_b32 v185, v81, v83, %[sb1]\n\t" \
  "v_cndmask_b32 v176, v184, v185, %[sb0]\n\t" \
  "v_cndmask_b32 v184, v84, v86, %[sb1]\n\t" \
  "v_cndmask_b32 v185, v85, v87, %[sb1]\n\t" \
  "v_cndmask_b32 v177, v184, v185, %[sb0]\n\t" \
  "v_cndmask_b32 v184, v88, v90, %[sb1]\n\t" \
  "v_cndmask_b32 v185, v89, v91, %[sb1]\n\t" \
  "v_cndmask_b32 v178, v184, v185, %[sb0]\n\t" \
  "v_cndmask_b32 v184, v92, v94, %[sb1]\n\t" \
  "v_cndmask_b32 v185, v93, v95, %[sb1]\n\t" \
  "v_cndmask_b32 v179, v184, v185, %[sb0]\n\t" \
  /* + A biases (unit's 4 gates, loaded previous step) */ \
  "s_waitcnt vmcnt(1)\n\t" \
  "v_add_f32 v176, v176, v" #PC0 "\n\t" \
  "v_add_f32 v177, v177, v" #PC1 "\n\t" \
  "v_add_f32 v178, v178, v" #PC2 "\n\t" \
  "v_add_f32 v179, v179, v" #PC3 "\n\t" \
  /* full 4-gate nonlinearity (r11-proven hazard-safe sequence) */ \
  "v_mul_f32 v180, s87, v176\n\t" \
  "v_mul_f32 v181, s87, v177\n\t" \
  "v_mul_f32 v182, s87, v179\n\t" \
  "v_mul_f32 v183, s88, v178\n\t" \
  "v_exp_f32 v180, v180\n\t" \
  "v_exp_f32 v181, v181\n\t" \
  "v_exp_f32 v182, v182\n\t" \
  "v_exp_f32 v183, v183\n\t" \
  "v_add_f32 v180, 1.0, v180\n\t" \
  "v_add_f32 v181, 1.0, v181\n\t" \
  "v_add_f32 v182, 1.0, v182\n\t" \
  "v_add_f32 v183, 1.0, v183\n\t" \
  "v_rcp_f32 v183, v183\n\t" \
  "v_rcp_f32 v180, v180\n\t" \
  "v_rcp_f32 v181, v181\n\t" \
  "v_rcp_f32 v182, v182\n\t" \
  "v_add_f32 v183, v183, v183\n\t" \
  "v_add_f32 v183, -1.0, v183\n\t" \
  "v_mul_f32 v184, v180, v183\n\t" \
  "v_fma_f32 v190, v181, v190, v184\n\t" \
  "v_mul_f32 v185, s88, v190\n\t" \
  "v_exp_f32 v185, v185\n\t" \
  "s_nop 1\n\t" \
  "v_add_f32 v185, 1.0, v185\n\t" \
  "v_rcp_f32 v185, v185\n\t" \
  "s_nop 1\n\t" \
  "v_fma_f32 v185, v185, 2.0, -1.0\n\t" \
  "v_mul_f32 v188, v182, v185\n\t" \
  "v_cvt_f16_f32 v188, v188\n\t" \
  /* write h f16 (lanes with (l&12)==0) */ \
  "s_and_saveexec_b64 s[84:85], s[82:83]\n\t" \
  "ds_write_b16 %[wr], v188 offset:" #WOFF "\n\t" \
  "s_mov_b64 exec, s[84:85]\n\t" \
  "s_waitcnt lgkmcnt(0)\n\t" \
  "s_barrier\n\t"

__global__ __launch_bounds__(512, 2)
__attribute__((amdgpu_waves_per_eu(2, 2)))
void lstm_kernel(
    const float* __restrict__ A,      // (T,128,4)
    const float* __restrict__ W_hh,   // (512,128)
    const float* __restrict__ W_fc,   // (5,128)
    const float* __restrict__ b_fc,   // (5,)
    float* __restrict__ out)          // (5,)
{
    const int tid  = threadIdx.x;            // 0..511
    const int lane = tid & 63;
    const int wave = tid >> 6;               // 0..7
    const int q0   = wave * 16;              // first unit of this wave
    const int row  = lane & 15;              // A-fragment row
    const int kb8  = (lane >> 4) * 8;        // A/B fragment K-chunk base
    const int u    = q0 + 4 * (lane >> 4) + (lane & 3);  // this lane's unit

    // h as f16: 2 buffers x 128 f16 = 512 B, linear layout
    __shared__ __align__(16) float h_s[2][64];

    if (tid < 128) ((float*)h_s)[tid] = 0.f;  // h_{-1} = 0 (both bufs)
    __syncthreads();

    // per-lane fragment addresses (row l&15, K base (l>>4)*8; kt via imm offs)
    const unsigned long long wai = (unsigned long long)(uintptr_t)(W_hh + (size_t)(q0 + row)        * D_LSTM + kb8);
    const unsigned long long waf = (unsigned long long)(uintptr_t)(W_hh + (size_t)(128 + q0 + row)  * D_LSTM + kb8);
    const unsigned long long wag = (unsigned long long)(uintptr_t)(W_hh + (size_t)(256 + q0 + row)  * D_LSTM + kb8);
    const unsigned long long wao = (unsigned long long)(uintptr_t)(W_hh + (size_t)(384 + q0 + row)  * D_LSTM + kb8);
    const unsigned int atid = (unsigned int)(u * 16);            // A byte off (unit's dwordx4)
    const unsigned int lds0 = (unsigned int)(uintptr_t)&h_s[0][0];
    const unsigned int rb   = lds0 + (unsigned int)((lane >> 4) * 16);  // B-frag read base
    const unsigned int wr   = lds0 + (unsigned int)(u * 2);             // h write addr
    const unsigned long long wm  = __ballot((lane & 12) == 0);   // 16 writer lanes
    const unsigned long long sb0 = __ballot(lane & 1);
    const unsigned long long sb1 = __ballot(lane & 2);

    asm volatile(
        // ---- prologue: consts; pack weight fragments f32->f16 into v0-63 ----
        "s_mov_b32 s80, 2048\n\t"
        "s_mov_b32 s86, 4096\n\t"
        "s_mov_b32 s87, 0xBFB8AA3B\n\t"     // -log2(e)
        "s_mov_b32 s88, 0xC038AA3B\n\t"     // -2*log2(e)
        "s_mov_b64 s[82:83], %[wm]\n\t"
        FRAGLOAD(wai)
        ROWPACK(0,1,2,3,4,5,6,7,8,9,10,11,12,13,14,15)
        FRAGLOAD(waf)
        ROWPACK(16,17,18,19,20,21,22,23,24,25,26,27,28,29,30,31)
        FRAGLOAD(wag)
        ROWPACK(32,33,34,35,36,37,38,39,40,41,42,43,44,45,46,47)
        FRAGLOAD(wao)
        ROWPACK(48,49,50,51,52,53,54,55,56,57,58,59,60,61,62,63)
        // zero C operand + c state; load A row 0
        "v_mov_b32 v164, 0\n\t"
        "v_mov_b32 v165, 0\n\t"
        "v_mov_b32 v166, 0\n\t"
        "v_mov_b32 v167, 0\n\t"
        "global_load_dwordx4 v[168:171], %[at], %[ab]\n\t"
        "s_waitcnt vmcnt(0)\n\t"
        "v_mov_b32 v190, 0\n\t"             // c = 0
        "1:\n\t"
        // even step: read buf0 (+0), consume v168-171, prefetch v172-175, write buf1 (+256)
        HALF(172,175, 168,169,170,171, 0,64,128,192, 256)
        // odd step: read buf1 (+256), consume v172-175, prefetch v168-171, write buf0 (+0)
        HALF(168,171, 172,173,174,175, 256,320,384,448, 0)
        "s_sub_u32 s86, s86, 1\n\t"
        "s_cmp_lg_u32 s86, 0\n\t"
        "s_cbranch_scc1 1b\n\t"
        :
        : [wai]"v"(wai), [waf]"v"(waf), [wag]"v"(wag), [wao]"v"(wao),
          [ab]"s"(A), [at]"v"(atid), [rb]"v"(rb), [wr]"v"(wr), [wm]"s"(wm),
          [sb0]"s"(sb0), [sb1]"s"(sb1)
        : "v0","v1","v2","v3","v4","v5","v6","v7","v8","v9",
          "v10","v11","v12","v13","v14","v15","v16","v17","v18","v19",
          "v20","v21","v22","v23","v24","v25","v26","v27","v28","v29",
          "v30","v31","v32","v33","v34","v35","v36","v37","v38","v39",
          "v40","v41","v42","v43","v44","v45","v46","v47","v48","v49",
          "v50","v51","v52","v53","v54","v55","v56","v57","v58","v59",
          "v60","v61","v62","v63","v64","v65","v66","v67","v68","v69",
          "v70","v71","v72","v73","v74","v75","v76","v77","v78","v79",
          "v80","v81","v82","v83","v84","v85","v86","v87","v88","v89",
          "v90","v91","v92","v93","v94","v95","v96","v97","v98","v99",
          "v100","v101","v102","v103","v104","v105","v106","v107","v108","v109",
          "v110","v111","v112","v113","v114","v115","v116","v117","v118","v119",
          "v120","v121","v122","v123","v124","v125","v126","v127","v128","v129",
          "v130","v131","v132","v133","v134","v135","v136","v137","v138","v139",
          "v140","v141","v142","v143","v144","v145","v146","v147","v148","v149",
          "v150","v151","v152","v153","v154","v155","v156","v157","v158","v159",
          "v160","v161","v162","v163","v164","v165","v166","v167","v168","v169",
          "v170","v171","v172","v173","v174","v175","v176","v177","v178","v179",
          "v180","v181","v182","v183","v184","v185","v186","v187","v188","v189",
          "v190","v191",
          "s80","s81","s82","s83","s84","s85","s86","s87","s88",
          "scc","memory"
    );

    __syncthreads();

    // final FC: out = hT @ W_fc.T + b_fc  (final h in buffer 0, f16, linear)
    if (tid < N_CLS) {
        const __half* hh = (const __half*)&h_s[0][0];
        float acc = b_fc[tid];
        #pragma unroll
        for (int k = 0; k < D_LSTM; ++k) {
            acc += __half2float(hh[k]) * W_fc[tid * D_LSTM + k];
        }
        out[tid] = acc;
    }
}

// ---------------------------------------------------------------------------
extern "C" void kernel_launch(void* const* d_in, const int* in_sizes, int n_in,
                              void* d_out, int out_size, void* d_ws, size_t ws_size,
                              hipStream_t stream) {
    const float* x       = (const float*)d_in[0];
    const int*   esrc    = (const int*)  d_in[1];
    const int*   edst    = (const int*)  d_in[2];
    const float* W_rel1  = (const float*)d_in[3];
    const float* b_rel1  = (const float*)d_in[4];
    const float* W_root1 = (const float*)d_in[5];
    const float* W_rel2  = (const float*)d_in[6];
    const float* b_rel2  = (const float*)d_in[7];
    const float* W_root2 = (const float*)d_in[8];
    const float* W_ih    = (const float*)d_in[9];
    const float* W_hh    = (const float*)d_in[10];
    const float* b_ih    = (const float*)d_in[11];
    const float* b_hh    = (const float*)d_in[12];
    const float* W_fc    = (const float*)d_in[13];
    const float* b_fc    = (const float*)d_in[14];

    float* out = (float*)d_out;
    float* A   = (float*)d_ws;   // (T,128,4) f32 = 16 MB

    gnn_proj_kernel<<<T_LEN / TB, 64, 0, stream>>>(
        x, esrc, edst, W_rel1, b_rel1, W_root1,
        W_rel2, b_rel2, W_root2, W_ih, b_ih, b_hh, A);

    lstm_kernel<<<1, 512, 0, stream>>>(A, W_hh, W_fc, b_fc, out);
}